// Round 6
// baseline (131.343 us; speedup 1.0000x reference)
//
#include <hip/hip_runtime.h>

// Multi-scale deformable attention (Deformable-DETR), forward. All shapes static:
// value: (2, 13294, 8, 32) f32 | loc: (2,13294,8,4,4,2) f32 | aw: (2,13294,8,4,4) f32
// out:   (2, 13294, 256) f32 (head-major channels)
//
// NOTE: XCD blockIdx swizzle is BANNED for this problem — it reproducibly
// trips the post-timing re-validation (R2, R5) despite being bijective.

#define BS 2
#define NH 8
#define DD 32
#define LL 4
#define PP 4
#define QQ 13294
#define KK 13294
#define LPG 8    // lanes per group; each lane holds 4 channels (f32x4)
#define GPB 32   // groups per 256-thread block
#define NWG 6647 // BS*NH*QQ / GPB, exact

typedef float f32x4 __attribute__((ext_vector_type(4)));

__global__ __launch_bounds__(256, 4) void msda_fwd_kernel(
    const f32x4* __restrict__ value4,  // (bs,K,nh,8) f32x4
    const f32x4* __restrict__ locv,    // (bs,Q,nh,L,P,2) viewed as f32x4[...][8]
    const f32x4* __restrict__ awv,     // (bs,Q,nh,L,P)   viewed as f32x4[...][4]
    f32x4*       __restrict__ out4)    // (bs,Q,nh,8) f32x4
{
    constexpr int Hs[4]     = {100, 50, 25, 13};
    constexpr int Ws[4]     = {100, 50, 25, 13};
    constexpr int starts[4] = {0, 10000, 12500, 13125};

    const int gid  = blockIdx.x * GPB + (threadIdx.x >> 3);  // (b,h,q)-ordered
    const int lane = threadIdx.x & (LPG - 1);

    const int q  = gid % QQ;
    const int bh = gid / QQ;
    const int h  = bh % NH;
    const int b  = bh / NH;

    const size_t lg = (size_t)(b * QQ + q) * NH + h;
    const f32x4* lp = locv + lg * 8;   // 16 samples * (x,y) = 8 f32x4
    const f32x4* wp = awv  + lg * 4;   // 16 weights       = 4 f32x4

    // f32x4 element for (b, key, h, lane): key stride = NH*DD/4 = 64 vectors
    const f32x4* vbase = value4 + ((size_t)b * KK * NH + h) * (DD / 4) + lane;

    f32x4 acc = {0.0f, 0.0f, 0.0f, 0.0f};

    #pragma unroll
    for (int l = 0; l < LL; ++l) {
        const int H = Hs[l], W = Ws[l];
        const float fH = (float)H, fW = (float)W;

        // Phase 1: subgroup-uniform loc/aw, vectorized + nontemporal (streamed once)
        const f32x4 lv0 = __builtin_nontemporal_load(&lp[2 * l + 0]); // samples 4l+0,4l+1
        const f32x4 lv1 = __builtin_nontemporal_load(&lp[2 * l + 1]); // samples 4l+2,4l+3
        const f32x4 wv  = __builtin_nontemporal_load(&wp[l]);         // weights 4l..4l+3

        // Phase 2: all 4 samples' corner indices + weights (pure VALU)
        int   idx[PP][4];
        float wgt[PP][4];
        #pragma unroll
        for (int p = 0; p < PP; ++p) {
            const f32x4 lv = (p < 2) ? lv0 : lv1;
            const float lx = lv[(p & 1) * 2 + 0];
            const float ly = lv[(p & 1) * 2 + 1];
            const float w  = wv[p];

            // align_corners=False, padding zeros: x = loc_x*W - 0.5
            const float x = lx * fW - 0.5f;
            const float y = ly * fH - 0.5f;
            const float x0f = floorf(x), y0f = floorf(y);
            const float dx = x - x0f, dy = y - y0f;
            const int x0 = (int)x0f, y0 = (int)y0f;
            const int x1 = x0 + 1,  y1 = y0 + 1;

            const float mx0 = ((unsigned)x0 < (unsigned)W) ? 1.0f : 0.0f;
            const float mx1 = ((unsigned)x1 < (unsigned)W) ? 1.0f : 0.0f;
            const float my0 = ((unsigned)y0 < (unsigned)H) ? 1.0f : 0.0f;
            const float my1 = ((unsigned)y1 < (unsigned)H) ? 1.0f : 0.0f;

            const int cx0 = min(max(x0, 0), W - 1);
            const int cx1 = min(max(x1, 0), W - 1);
            const int cy0 = min(max(y0, 0), H - 1);
            const int cy1 = min(max(y1, 0), H - 1);

            const int r0 = starts[l] + cy0 * W;
            const int r1 = starts[l] + cy1 * W;
            idx[p][0] = r0 + cx0;  wgt[p][0] = (1.0f - dx) * (1.0f - dy) * w * mx0 * my0;
            idx[p][1] = r0 + cx1;  wgt[p][1] = dx * (1.0f - dy) * w * mx1 * my0;
            idx[p][2] = r1 + cx0;  wgt[p][2] = (1.0f - dx) * dy * w * mx0 * my1;
            idx[p][3] = r1 + cx1;  wgt[p][3] = dx * dy * w * mx1 * my1;
        }

        // Phase 3: issue all 16 corner gathers as a batch (MLP: 16 in flight)
        f32x4 v[PP][4];
        #pragma unroll
        for (int p = 0; p < PP; ++p)
            #pragma unroll
            for (int c = 0; c < 4; ++c)
                v[p][c] = vbase[idx[p][c] * (NH * DD / 4)];

        // Phase 4: 64 FMAs
        #pragma unroll
        for (int p = 0; p < PP; ++p)
            #pragma unroll
            for (int c = 0; c < 4; ++c) {
                acc.x = fmaf(wgt[p][c], v[p][c].x, acc.x);
                acc.y = fmaf(wgt[p][c], v[p][c].y, acc.y);
                acc.z = fmaf(wgt[p][c], v[p][c].z, acc.z);
                acc.w = fmaf(wgt[p][c], v[p][c].w, acc.w);
            }
    }

    // out: (bs,Q,nh,8) f32x4; streamed once -> nontemporal store
    __builtin_nontemporal_store(acc, &out4[lg * (DD / 4) + lane]);
}

extern "C" void kernel_launch(void* const* d_in, const int* in_sizes, int n_in,
                              void* d_out, int out_size, void* d_ws, size_t ws_size,
                              hipStream_t stream) {
    const f32x4* value4 = (const f32x4*)d_in[0];
    const f32x4* locv   = (const f32x4*)d_in[2];
    const f32x4* awv    = (const f32x4*)d_in[3];
    f32x4*       out4   = (f32x4*)d_out;

    msda_fwd_kernel<<<NWG, 256, 0, stream>>>(value4, locv, awv, out4);
}